// Round 2
// baseline (4424.709 us; speedup 1.0000x reference)
//
#include <hip/hip_runtime.h>

// GRU scan T=1024,B=256,D=H=256 — 3-kernel design:
//  1) transpose_w: Wi,Wh (f32 [256][768]) -> Wt,Wht (bf16 [768][256], k-fast)
//  2) gi_gemm: per 128-step window, gi = x @ Wi  (full chip, no seq dependency)
//  3) rec_kernel: persistent 16 blocks x 1024 thr; Wh_r/Wh_z in VGPR frags,
//     Wh_n in LDS, h chain f32 in regs + bf16 in LDS for MFMA A-frags.
// Inputs are FLOAT32 per harness doc (round-0 NaN = f32 misread as bf16).

typedef __attribute__((ext_vector_type(8))) short sv8;
typedef __attribute__((ext_vector_type(4))) short sv4;
typedef __attribute__((ext_vector_type(4))) float fv4;

#define HPAD 264
#define GAP 40

static __device__ __forceinline__ unsigned short f2bf(float f) {
  unsigned int u = __float_as_uint(f);
  u += 0x7fffu + ((u >> 16) & 1u);  // RNE
  return (unsigned short)(u >> 16);
}
static __device__ __forceinline__ float bf2f(unsigned short s) {
  return __uint_as_float(((unsigned int)s) << 16);
}

// ---------------- kernel 1: weight transpose + bf16 cast ----------------
__global__ __launch_bounds__(256) void transpose_w(
    const float* __restrict__ Wi, const float* __restrict__ Wh,
    unsigned short* __restrict__ Wt, unsigned short* __restrict__ Wht) {
  __shared__ float tile[32][33];
  const int bid = blockIdx.x;                 // 0..383
  const float* src = (bid < 192) ? Wi : Wh;
  unsigned short* dst = (bid < 192) ? Wt : Wht;
  const int local = bid % 192;
  const int c0 = (local % 24) * 32;           // col in [0,768)
  const int k0 = (local / 24) * 32;           // k in [0,256)
  const int t = threadIdx.x, tr = t >> 5, tc = t & 31;
#pragma unroll
  for (int p = 0; p < 4; ++p) {
    int k = tr + p * 8;
    tile[k][tc] = src[(size_t)(k0 + k) * 768 + c0 + tc];
  }
  __syncthreads();
#pragma unroll
  for (int p = 0; p < 4; ++p) {
    int c = tr + p * 8;
    dst[(size_t)(c0 + c) * 256 + k0 + tc] = f2bf(tile[tc][c]);
  }
}

// ---------------- kernel 2: gi = x @ Wi for a window ----------------
// grid (wsteps*2, 6), 256 thr. BM=BN=128, BK=32.
__global__ __launch_bounds__(256) void gi_gemm(
    const float* __restrict__ ins, const unsigned short* __restrict__ Wt,
    unsigned short* __restrict__ gi, int w0) {
  __shared__ __align__(16) unsigned short As[128][GAP];
  __shared__ __align__(16) unsigned short Bs[128][GAP];
  const int t = threadIdx.x;
  const int m0 = blockIdx.x * 128;
  const int n0 = blockIdx.y * 128;
  const int wave = t >> 6, lane = t & 63;
  const int n16 = lane & 15, quad = lane >> 4;
  const int m0w = (wave & 1) * 64, n0w = (wave >> 1) * 64;

  fv4 acc[4][4] = {};
  for (int kb = 0; kb < 8; ++kb) {
    // stage A: x rows (f32 -> bf16)
#pragma unroll
    for (int r = 0; r < 4; ++r) {
      const int m = (t >> 3) + r * 32;
      const int kk = (t & 7) * 4;
      const int grow = m0 + m;  // (lt,b) row
      const float* xp = ins + ((size_t)(w0 + (grow >> 8)) * 256 + (grow & 255)) * 256 + kb * 32 + kk;
      fv4 v = *(const fv4*)xp;
      sv4 pk = {(short)f2bf(v[0]), (short)f2bf(v[1]), (short)f2bf(v[2]), (short)f2bf(v[3])};
      *(sv4*)&As[m][kk] = pk;
    }
    // stage B: straight bf16 copy from pre-transposed Wt
    {
      const int n = t >> 1, kh = (t & 1) * 16;
      const sv8* wp = (const sv8*)(Wt + (size_t)(n0 + n) * 256 + kb * 32 + kh);
      *(sv8*)&Bs[n][kh] = wp[0];
      *(sv8*)&Bs[n][kh + 8] = wp[1];
    }
    __syncthreads();
    sv8 af[4], bfr[4];
#pragma unroll
    for (int mt = 0; mt < 4; ++mt) af[mt] = *(const sv8*)&As[m0w + mt * 16 + n16][quad * 8];
#pragma unroll
    for (int nt = 0; nt < 4; ++nt) bfr[nt] = *(const sv8*)&Bs[n0w + nt * 16 + n16][quad * 8];
#pragma unroll
    for (int mt = 0; mt < 4; ++mt)
#pragma unroll
      for (int nt = 0; nt < 4; ++nt)
        acc[mt][nt] = __builtin_amdgcn_mfma_f32_16x16x32_bf16(af[mt], bfr[nt], acc[mt][nt], 0, 0, 0);
    __syncthreads();
  }
#pragma unroll
  for (int mt = 0; mt < 4; ++mt)
#pragma unroll
    for (int i = 0; i < 4; ++i) {
      const int row = m0 + m0w + mt * 16 + quad * 4 + i;
      unsigned short* gp = gi + (size_t)row * 768 + n0 + n0w + n16;
#pragma unroll
      for (int nt = 0; nt < 4; ++nt) gp[nt * 16] = f2bf(acc[mt][nt][i]);
    }
}

// ---------------- kernel 3: recurrent scan over a window ----------------
__global__ __launch_bounds__(1024) void rec_kernel(
    const unsigned short* __restrict__ gi,   // [wsteps*256][768] bf16
    const int* __restrict__ resets,          // [T][B] int32
    const float* __restrict__ h_in,          // [B][H] f32 (init_h or h_carry)
    float* __restrict__ h_carry,             // [B][H] f32
    const unsigned short* __restrict__ Wht,  // [768][256] bf16 transposed
    const float* __restrict__ bias,          // [768] f32
    float* __restrict__ out,                 // [T][B][H] f32
    int t0, int wsteps) {
  __shared__ __align__(16) unsigned short whn[256][HPAD];     // Wh_n, [col][k]
  __shared__ __align__(16) unsigned short hbuf[2][16][HPAD];  // h bf16

  const int tid = threadIdx.x;
  const int wave = tid >> 6, lane = tid & 63;
  const int n16 = lane & 15, quad = lane >> 4;
  const int row0 = blockIdx.x * 16;
  const int wcb = wave * 16;

  // stage Wh_n (cols 512..767 of Wht) into LDS
  for (int e = tid; e < 8192; e += 1024) {
    const int col = e >> 5, kc = (e & 31) * 8;
    *(sv8*)&whn[col][kc] = *(const sv8*)(Wht + (size_t)(512 + col) * 256 + kc);
  }
  // Wh_r / Wh_z B-frags in VGPRs
  sv8 whf[2][8];
#pragma unroll
  for (int g = 0; g < 2; ++g)
#pragma unroll
    for (int kt = 0; kt < 8; ++kt)
      whf[g][kt] = *(const sv8*)(Wht + (size_t)(g * 256 + wcb + n16) * 256 + kt * 32 + quad * 8);

  const float b_r = bias[wcb + n16];
  const float b_z = bias[256 + wcb + n16];
  const float b_n = bias[512 + wcb + n16];

  // stage hbuf[0] = bf16(h_in) pre-masked with resets[t0]
  {
    const int row = tid >> 6, c4 = (tid & 63) * 4;
    const int f = resets[(size_t)t0 * 256 + row0 + row];
    fv4 v = *(const fv4*)(h_in + (size_t)(row0 + row) * 256 + c4);
    sv4 pk;
#pragma unroll
    for (int j = 0; j < 4; ++j) pk[j] = f ? (short)0 : (short)f2bf(v[j]);
    *(sv4*)&hbuf[0][row][c4] = pk;
  }
  float hprev[4];
#pragma unroll
  for (int i = 0; i < 4; ++i)
    hprev[i] = h_in[(size_t)(row0 + quad * 4 + i) * 256 + wcb + n16];
  __syncthreads();

  const unsigned short* gip = gi + (size_t)(row0 + quad * 4) * 768 + wcb + n16;
  const int* rp = resets + (size_t)t0 * 256 + row0;
  float* op = out + (size_t)t0 * 65536 + (size_t)(row0 + quad * 4) * 256 + wcb + n16;

  for (int s = 0; s < wsteps; ++s) {
    const int rb = s & 1, wb = rb ^ 1;

    unsigned short gr[4], gz[4], gn[4];
#pragma unroll
    for (int i = 0; i < 4; ++i) {
      const unsigned short* g0 = gip + (size_t)(s * 256 + i) * 768;
      gr[i] = g0[0]; gz[i] = g0[256]; gn[i] = g0[512];
    }
    int rc[4], nf[4];
#pragma unroll
    for (int i = 0; i < 4; ++i) rc[i] = rp[quad * 4 + i];
    const bool hasn = (s + 1 < wsteps);
#pragma unroll
    for (int i = 0; i < 4; ++i) nf[i] = hasn ? rp[256 + quad * 4 + i] : 0;

    fv4 acc_r = {}, acc_z = {}, acc_n = {};
#pragma unroll
    for (int kt = 0; kt < 8; ++kt) {
      sv8 hf = *(const sv8*)&hbuf[rb][n16][kt * 32 + quad * 8];
      sv8 wnf = *(const sv8*)&whn[wcb + n16][kt * 32 + quad * 8];
      acc_r = __builtin_amdgcn_mfma_f32_16x16x32_bf16(hf, whf[0][kt], acc_r, 0, 0, 0);
      acc_z = __builtin_amdgcn_mfma_f32_16x16x32_bf16(hf, whf[1][kt], acc_z, 0, 0, 0);
      acc_n = __builtin_amdgcn_mfma_f32_16x16x32_bf16(hf, wnf, acc_n, 0, 0, 0);
    }

#pragma unroll
    for (int i = 0; i < 4; ++i) {
      const float pre_r = bf2f(gr[i]) + acc_r[i] + b_r;
      const float pre_z = bf2f(gz[i]) + acc_z[i] + b_z;
      const float r = 1.f / (1.f + __expf(-pre_r));
      const float z = 1.f / (1.f + __expf(-pre_z));
      const float n = tanhf(bf2f(gn[i]) + r * (acc_n[i] + b_n));
      const float hp = rc[i] ? 0.f : hprev[i];
      const float hnew = (1.f - z) * n + z * hp;
      op[i * 256] = hnew;
      hprev[i] = hnew;
      hbuf[wb][quad * 4 + i][wcb + n16] = nf[i] ? (unsigned short)0 : f2bf(hnew);
    }
    op += 65536;
    rp += 256;
    __syncthreads();
  }
#pragma unroll
  for (int i = 0; i < 4; ++i)
    h_carry[(size_t)(row0 + quad * 4 + i) * 256 + wcb + n16] = hprev[i];
}

extern "C" void kernel_launch(void* const* d_in, const int* in_sizes, int n_in,
                              void* d_out, int out_size, void* d_ws, size_t ws_size,
                              hipStream_t stream) {
  const float* ins    = (const float*)d_in[0];
  const int* resets   = (const int*)d_in[1];
  const float* init_h = (const float*)d_in[2];
  const float* Wi     = (const float*)d_in[3];
  const float* Wh     = (const float*)d_in[4];
  const float* bias   = (const float*)d_in[5];
  float* out          = (float*)d_out;

  char* ws = (char*)d_ws;
  unsigned short* Wt  = (unsigned short*)ws;              // 393216 B
  unsigned short* Wht = (unsigned short*)(ws + 393216);   // 393216 B
  float* h_carry      = (float*)(ws + 786432);            // 262144 B
  unsigned short* gi  = (unsigned short*)(ws + 1048576);

  int wsteps = 128;
  while (wsteps > 2 && (size_t)1048576 + (size_t)wsteps * 256 * 768 * 2 > ws_size) wsteps >>= 1;
  const int nwin = 1024 / wsteps;

  hipLaunchKernelGGL(transpose_w, dim3(384), dim3(256), 0, stream, Wi, Wh, Wt, Wht);
  for (int w = 0; w < nwin; ++w) {
    const int t0 = w * wsteps;
    hipLaunchKernelGGL(gi_gemm, dim3(wsteps * 2, 6), dim3(256), 0, stream, ins, Wt, gi, t0);
    hipLaunchKernelGGL(rec_kernel, dim3(16), dim3(1024), 0, stream,
                       gi, resets, (w == 0 ? init_h : h_carry), h_carry, Wht, bias, out, t0, wsteps);
  }
}